// Round 8
// baseline (74.391 us; speedup 1.0000x reference)
//
#include <hip/hip_runtime.h>

typedef __attribute__((ext_vector_type(4))) float  f32x4;
typedef __attribute__((ext_vector_type(8))) short  short8;
typedef __attribute__((ext_vector_type(4))) unsigned int u32x4;
typedef __attribute__((ext_vector_type(2))) unsigned int u32x2;

#define NN 200
#define EDIM 128
#define FDIM 16
#define BN_TOTAL 1600
#define LAMBDA 2.8853900817779268f   // 2*log2(e): exp2(LAMBDA*x) = e^{2x}

// ws layout. bf16 (short offsets):
#define WS_WN 0        // W_node  [128][128]
#define WS_WE 16384    // W_edge  [128][16]
#define WS_WW 18432    // W_weight[128]
#define WS_WO 18560    // W_out   [128][128]
#define WS_H  34944    // h       [1600][128]
// f32 (float offsets): starts right after shorts (byte 479488, 16B aligned)
#define WSF_PART 119872   // part [7][1600][128]

#define SETUP_CHUNKS 59936   // f32x4 chunks: 4096 WN + 512 WE + 32 WW + 4096 WO + 51200 H

__device__ __forceinline__ unsigned short f2bf(float f) {
    unsigned u = __float_as_uint(f);
    u += 0x7FFFu + ((u >> 16) & 1u);   // RNE
    return (unsigned short)(u >> 16);
}
__device__ __forceinline__ unsigned cvtpk(float lo, float hi) {
    unsigned r;
    asm("v_cvt_pk_bf16_f32 %0, %1, %2" : "=v"(r) : "v"(lo), "v"(hi));
    return r;
}
// rcp(1 + exp2(x)) = 1/(1+e^{2 arg}) when x = LAMBDA*arg; tanh = 1 - 2*this
__device__ __forceinline__ float sigr(float x) {
    return __builtin_amdgcn_rcpf(1.0f + __builtin_amdgcn_exp2f(x));
}

// ---------------------------------------------------------------------------
// setup: pure bf16 conversion streamer (no GEMM, no scaling). 235 x 256.
// ---------------------------------------------------------------------------
__global__ __launch_bounds__(256) void setup_kernel(
    const float* __restrict__ h, const float* __restrict__ W_node,
    const float* __restrict__ W_edge, const float* __restrict__ W_weight,
    const float* __restrict__ W_out, unsigned short* __restrict__ wsb)
{
    int c = blockIdx.x * 256 + threadIdx.x;
    if (c >= SETUP_CHUNKS) return;
    const float* src; unsigned short* dst;
    if (c < 4096)      { src = W_node   + c * 4;            dst = wsb + WS_WN + c * 4; }
    else if (c < 4608) { src = W_edge   + (c - 4096) * 4;   dst = wsb + WS_WE + (c - 4096) * 4; }
    else if (c < 4640) { src = W_weight + (c - 4608) * 4;   dst = wsb + WS_WW + (c - 4608) * 4; }
    else if (c < 8736) { src = W_out    + (c - 4640) * 4;   dst = wsb + WS_WO + (c - 4640) * 4; }
    else               { src = h + (size_t)(c - 8736) * 4;  dst = wsb + WS_H  + (size_t)(c - 8736) * 4; }
    f32x4 v = *(const f32x4*)src;
    u32x2 pk = { (unsigned)f2bf(v.x) | ((unsigned)f2bf(v.y) << 16),
                 (unsigned)f2bf(v.z) | ((unsigned)f2bf(v.w) << 16) };
    *(u32x2*)dst = pk;
}

// ---------------------------------------------------------------------------
// msg: 11200 single-wave blocks; block = item (bn, cj) = 32 m-rows x 128 e.
// Computes hi on the fly (32 broadcast-row MFMAs from bf16 W_node in L2),
// then the edge/weight projection (16 MFMAs, C-input = LAMBDA*hi) with the
// poison K-channel (k17: A=1 on pad rows, B=2^20 -> exp2=inf -> rcp=0).
// LAMBDA is folded into the A-side (ef, Wadj) and the C splat.
// Store: two fully coalesced 256B wave stores (r7 fix).
// ---------------------------------------------------------------------------
__global__ __launch_bounds__(64, 4) void msg_kernel(
    const float* __restrict__ ef, const float* __restrict__ Wadj,
    const unsigned short* __restrict__ wsb, float* __restrict__ part)
{
    const int lane = threadIdx.x;
    const int g    = lane >> 4;
    const int l15  = lane & 15;

    const int id = blockIdx.x;                 // < 11200
    const int bn = (id * 18725) >> 17;         // id/7 (exact for id < 43690)
    const int cj = id - bn * 7;

    // ---- HBM loads first: ef rows / Wadj ----
    f32x4 be[4];
#pragma unroll
    for (int t = 0; t < 2; ++t) {
        int row  = cj * 32 + t * 16 + l15;
        int rowc = row > NN - 1 ? NN - 1 : row;
        if (g < 2) {
            const float* p = ef + ((size_t)bn * NN + rowc) * FDIM + g * 8;
            be[t * 2]     = *(const f32x4*)p;
            be[t * 2 + 1] = *(const f32x4*)(p + 4);
        } else if (g == 2) {
            be[t * 2].x = Wadj[bn * NN + rowc];
        }
    }

    // ---- B fragments for the edge/weight projection (raw weights) ----
    short8 bfrag[8];
#pragma unroll
    for (int et = 0; et < 8; ++et) {
        short8 b = {0, 0, 0, 0, 0, 0, 0, 0};
        if (g < 2) b = *(const short8*)(wsb + WS_WE + (et * 16 + l15) * FDIM + g * 8);
        else if (g == 2) {
            b[0] = (short)wsb[WS_WW + et * 16 + l15];
            b[1] = (short)0x4980;                      // bf16 2^20 poison
        }
        bfrag[et] = b;
    }

    // ---- hi on the fly: A[r][k] = h[k] broadcast, B = W_node (bf16, L2) ----
    short8 ha[4];
#pragma unroll
    for (int ks = 0; ks < 4; ++ks)
        ha[ks] = *(const short8*)(wsb + WS_H + (size_t)bn * EDIM + ks * 32 + g * 8);
    float bh[8];
#pragma unroll
    for (int et = 0; et < 8; ++et) {
        f32x4 hc = {0.f, 0.f, 0.f, 0.f};
#pragma unroll
        for (int ks = 0; ks < 4; ++ks) {
            short8 wn = *(const short8*)(wsb + WS_WN + (et * 16 + l15) * EDIM + ks * 32 + g * 8);
            hc = __builtin_amdgcn_mfma_f32_16x16x32_bf16(ha[ks], wn, hc, 0, 0, 0);
        }
        bh[et] = hc[0] * LAMBDA;                // all D rows equal -> take [0]
    }

    // ---- edge/weight projection + sigr accumulation ----
    float Sr[8];
#pragma unroll
    for (int et = 0; et < 8; ++et) Sr[et] = 0.f;

#pragma unroll
    for (int t = 0; t < 2; ++t) {
        short8 a;
        if (g < 2) {                            // k 0..15 = LAMBDA*ef
            u32x4 pk = { cvtpk(LAMBDA * be[t*2].x,   LAMBDA * be[t*2].y),
                         cvtpk(LAMBDA * be[t*2].z,   LAMBDA * be[t*2].w),
                         cvtpk(LAMBDA * be[t*2+1].x, LAMBDA * be[t*2+1].y),
                         cvtpk(LAMBDA * be[t*2+1].z, LAMBDA * be[t*2+1].w) };
            a = __builtin_bit_cast(short8, pk);
        } else {
            short8 z = {0,0,0,0,0,0,0,0};
            if (g == 2) {
                z[0] = (short)f2bf(LAMBDA * be[t*2].x);      // k16 = LAMBDA*W[m]
                if (cj * 32 + t * 16 + l15 >= NN) z[1] = (short)0x4980;  // pad poison
            }
            a = z;
        }
#pragma unroll
        for (int et = 0; et < 8; ++et) {
            f32x4 c = {bh[et], bh[et], bh[et], bh[et]};
            c = __builtin_amdgcn_mfma_f32_16x16x32_bf16(a, bfrag[et], c, 0, 0, 0);
            Sr[et] += sigr(c[0]) + sigr(c[1]) + sigr(c[2]) + sigr(c[3]);
        }
    }

    // ---- reduce across g-groups: every lane then holds all 8 sums ----
#pragma unroll
    for (int et = 0; et < 8; ++et) {
        float p = Sr[et];
        p += __shfl_xor(p, 16);
        p += __shfl_xor(p, 32);
        Sr[et] = p;
    }

    // ---- two fully coalesced 256B wave stores ----
    {
        float v0 = (g == 0) ? Sr[0] : (g == 1) ? Sr[1] : (g == 2) ? Sr[2] : Sr[3];
        float v1 = (g == 0) ? Sr[4] : (g == 1) ? Sr[5] : (g == 2) ? Sr[6] : Sr[7];
        float* dst = part + ((size_t)cj * BN_TOTAL + bn) * EDIM;
        dst[lane]      = v0;
        dst[64 + lane] = v1;
    }
}

// ---------------------------------------------------------------------------
// outproj: 1600 single-wave blocks, one wave per bn row.
// agg[e] = 1 - 0.01 * sum_j part[j][bn][e]; A-frag gathered via shfl
// (no LDS, no barrier); out = agg @ W_out^T + b_out, coalesced stores.
// ---------------------------------------------------------------------------
__global__ __launch_bounds__(64) void outproj_kernel(
    const float* __restrict__ part, const unsigned short* __restrict__ wsb,
    const float* __restrict__ b_out, float* __restrict__ out)
{
    const int lane = threadIdx.x;
    const int g    = lane >> 4;
    const int l15  = lane & 15;
    const int bn   = blockIdx.x;

    float s0 = 0.f, s1 = 0.f;
#pragma unroll
    for (int j = 0; j < 7; ++j) {
        const float* p = part + ((size_t)j * BN_TOTAL + bn) * EDIM;
        s0 += p[lane];
        s1 += p[64 + lane];
    }
    const float a0 = __builtin_fmaf(-0.01f, s0, 1.0f);   // agg[lane]
    const float a1 = __builtin_fmaf(-0.01f, s1, 1.0f);   // agg[64+lane]

    // A fragments: af[ks] = bf16(agg[ks*32 + g*8 .. +7]), gathered via shfl
    short8 af[4];
#pragma unroll
    for (int ks = 0; ks < 4; ++ks) {
        const float src = (ks < 2) ? a0 : a1;
        const int base = (ks & 1) * 32 + g * 8;
        float t0 = __shfl(src, base + 0, 64);
        float t1 = __shfl(src, base + 1, 64);
        float t2 = __shfl(src, base + 2, 64);
        float t3 = __shfl(src, base + 3, 64);
        float t4 = __shfl(src, base + 4, 64);
        float t5 = __shfl(src, base + 5, 64);
        float t6 = __shfl(src, base + 6, 64);
        float t7 = __shfl(src, base + 7, 64);
        u32x4 pk = { cvtpk(t0, t1), cvtpk(t2, t3), cvtpk(t4, t5), cvtpk(t6, t7) };
        af[ks] = __builtin_bit_cast(short8, pk);
    }

    // out[f] = sum_k agg[k] * W_out[f][k]  (broadcast-row MFMAs, bf16 W_out)
    float o[8];
#pragma unroll
    for (int ft = 0; ft < 8; ++ft) {
        f32x4 acc = {0.f, 0.f, 0.f, 0.f};
#pragma unroll
        for (int ks = 0; ks < 4; ++ks) {
            short8 b = *(const short8*)(wsb + WS_WO + (ft * 16 + l15) * EDIM + ks * 32 + g * 8);
            acc = __builtin_amdgcn_mfma_f32_16x16x32_bf16(af[ks], b, acc, 0, 0, 0);
        }
        o[ft] = acc[0];                      // all D rows equal
    }

    const float v0 = (g == 0) ? o[0] : (g == 1) ? o[1] : (g == 2) ? o[2] : o[3];
    const float v1 = (g == 0) ? o[4] : (g == 1) ? o[5] : (g == 2) ? o[6] : o[7];
    out[(size_t)bn * EDIM + lane]      = v0 + b_out[lane];
    out[(size_t)bn * EDIM + 64 + lane] = v1 + b_out[64 + lane];
}

extern "C" void kernel_launch(void* const* d_in, const int* in_sizes, int n_in,
                              void* d_out, int out_size, void* d_ws, size_t ws_size,
                              hipStream_t stream) {
    const float* h        = (const float*)d_in[0];
    const float* ef       = (const float*)d_in[1];
    const float* W        = (const float*)d_in[2];
    const float* W_node   = (const float*)d_in[3];
    const float* W_edge   = (const float*)d_in[4];
    const float* W_weight = (const float*)d_in[5];
    const float* W_out    = (const float*)d_in[6];
    const float* b_out    = (const float*)d_in[7];
    float* out = (float*)d_out;

    unsigned short* wsb  = (unsigned short*)d_ws;
    float*          part = (float*)d_ws + WSF_PART;

    setup_kernel<<<(SETUP_CHUNKS + 255) / 256, 256, 0, stream>>>(
        h, W_node, W_edge, W_weight, W_out, wsb);
    msg_kernel<<<11200, 64, 0, stream>>>(ef, W, wsb, part);
    outproj_kernel<<<BN_TOTAL, 64, 0, stream>>>(part, wsb, b_out, out);
}

// Round 9
// 38.704 us; speedup vs baseline: 1.9220x; 1.9220x over previous
//
#include <hip/hip_runtime.h>

typedef __attribute__((ext_vector_type(4))) float  f32x4;
typedef __attribute__((ext_vector_type(8))) short  short8;
typedef __attribute__((ext_vector_type(4))) unsigned int u32x4;
typedef __attribute__((ext_vector_type(2))) unsigned int u32x2;

#define NN 200
#define EDIM 128
#define FDIM 16
#define BN_TOTAL 1600
#define NCHUNK 7                 // m-chunks of 32 rows
#define MSG_BLOCKS 2800          // 4 items per 64-thread (1-wave) block
#define LAMBDA 2.8853900817779268f   // 2*log2(e): exp2(LAMBDA*x) = e^{2x}

// ws layout (regions passed as separate __restrict__ pointers):
// shorts: [0,2048) W_edge*L, [2048,2176) W_weight*L, [2176,18560) W_out
// floats: [10240, 215040) hi*L [1600][128]; [215040, ...) part [7][1600][128]
#define WS_WOUT_S 2176
#define WSF_HI    10240
#define WSF_PART  215040

__device__ __forceinline__ unsigned short f2bf(float f) {
    unsigned u = __float_as_uint(f);
    u += 0x7FFFu + ((u >> 16) & 1u);   // RNE
    return (unsigned short)(u >> 16);
}
__device__ __forceinline__ short8 cvt8(f32x4 a, f32x4 b) {
    short8 r;
    r[0]=(short)f2bf(a.x); r[1]=(short)f2bf(a.y); r[2]=(short)f2bf(a.z); r[3]=(short)f2bf(a.w);
    r[4]=(short)f2bf(b.x); r[5]=(short)f2bf(b.y); r[6]=(short)f2bf(b.z); r[7]=(short)f2bf(b.w);
    return r;
}
__device__ __forceinline__ unsigned cvtpk(float lo, float hi) {
    unsigned r;
    asm("v_cvt_pk_bf16_f32 %0, %1, %2" : "=v"(r) : "v"(lo), "v"(hi));
    return r;
}
// rcp(1 + exp2(x)); x = LAMBDA*arg -> equals 1/(1+e^{2 arg}); tanh = 1 - 2*this
__device__ __forceinline__ float sigr(float x) {
    return __builtin_amdgcn_rcpf(1.0f + __builtin_amdgcn_exp2f(x));
}

// ---------------------------------------------------------------------------
// setup: blocks 0..199 -> hi = LAMBDA * (h @ W_node^T)   (16 rows x 64 e each)
//        blocks 200..207 -> bf16 convert of weights (W_edge/W_weight scaled)
// ---------------------------------------------------------------------------
__global__ __launch_bounds__(128) void setup_kernel(
    const float* __restrict__ h, const float* __restrict__ W_node,
    const float* __restrict__ W_edge, const float* __restrict__ W_weight,
    const float* __restrict__ W_out,
    unsigned short* __restrict__ wcvt,   // W_edge(0..2047) + W_weight(2048..2175)
    unsigned short* __restrict__ wout,   // W_out bf16 [128][128]
    float* __restrict__ hi_arr)          // [1600][128]
{
    const int blk = blockIdx.x;
    const int tid = threadIdx.x;

    if (blk < 200) {
        const int rb   = blk >> 1;
        const int eh   = blk & 1;
        const int lane = tid & 63;
        const int w    = tid >> 6;        // 0..1
        const int g    = lane >> 4;
        const int l15  = lane & 15;
        const int r0   = rb * 16;

        short8 afr[4];
#pragma unroll
        for (int ks = 0; ks < 4; ++ks) {
            const float* p = h + (size_t)(r0 + l15) * EDIM + ks * 32 + g * 8;
            afr[ks] = cvt8(*(const f32x4*)p, *(const f32x4*)(p + 4));
        }
#pragma unroll
        for (int e2 = 0; e2 < 2; ++e2) {
            const int et = eh * 4 + w * 2 + e2;
            f32x4 acc = {0.f, 0.f, 0.f, 0.f};
#pragma unroll
            for (int ks = 0; ks < 4; ++ks) {
                const float* p = W_node + (size_t)(et * 16 + l15) * EDIM + ks * 32 + g * 8;
                short8 bfr = cvt8(*(const f32x4*)p, *(const f32x4*)(p + 4));
                acc = __builtin_amdgcn_mfma_f32_16x16x32_bf16(afr[ks], bfr, acc, 0, 0, 0);
            }
#pragma unroll
            for (int r = 0; r < 4; ++r)
                hi_arr[(size_t)(r0 + g * 4 + r) * EDIM + et * 16 + l15] = acc[r] * LAMBDA;
        }
    } else {
        // 4640 f32x4 chunks: [0,512) W_edge*L, [512,544) W_weight*L, [544,4640) W_out
        for (int c = (blk - 200) * 128 + tid; c < 4640; c += 8 * 128) {
            const float* src; unsigned short* dst; float sc;
            if (c < 512)      { src = W_edge   + c * 4;         dst = wcvt + c * 4;               sc = LAMBDA; }
            else if (c < 544) { src = W_weight + (c - 512) * 4; dst = wcvt + 2048 + (c - 512) * 4; sc = LAMBDA; }
            else              { src = W_out    + (c - 544) * 4; dst = wout + (c - 544) * 4;        sc = 1.0f; }
            f32x4 v = *(const f32x4*)src;
            v.x *= sc; v.y *= sc; v.z *= sc; v.w *= sc;
            u32x2 pk = { (unsigned)f2bf(v.x) | ((unsigned)f2bf(v.y) << 16),
                         (unsigned)f2bf(v.z) | ((unsigned)f2bf(v.w) << 16) };
            *(u32x2*)dst = pk;
        }
    }
}

// ---------------------------------------------------------------------------
// msg: 2800 single-wave blocks x 4 items; item = (bn, cj) = 32 m-rows.
// Register-double-buffered pipeline (r5 shape: weights loaded ONCE per wave,
// every load for item i+1 issued before item i's compute); branch-free body
// (poison K-channel k17: A=2^20 on pad rows, B=2^20 -> exp2=inf -> rcp=0).
// Store (r7 fix): after the xor-reduce every lane holds all 8 sums, so lane
// (g,l15) writes elements lane and 64+lane -> two fully coalesced 256B wave
// stores (the old 16-lane scatter caused 13x HBM write amplification).
// ---------------------------------------------------------------------------
#define LOAD_ITEM(BE, BH, BN, CJ)                                             \
  do {                                                                        \
    _Pragma("unroll")                                                         \
    for (int t_ = 0; t_ < 2; ++t_) {                                          \
      int row_  = (CJ) * 32 + t_ * 16 + l15;                                  \
      int rowc_ = row_ > NN - 1 ? NN - 1 : row_;                              \
      if (g < 2) {                                                            \
        const float* p_ = ef + ((size_t)(BN) * NN + rowc_) * FDIM + g * 8;    \
        BE[t_ * 2]     = *(const f32x4*)p_;                                   \
        BE[t_ * 2 + 1] = *(const f32x4*)(p_ + 4);                             \
      } else if (g == 2) {                                                    \
        BE[t_ * 2].x = Wadj[(BN) * NN + rowc_];                               \
      }                                                                       \
    }                                                                         \
    _Pragma("unroll")                                                         \
    for (int et_ = 0; et_ < 8; ++et_)                                         \
      BH[et_] = hi_arr[(size_t)(BN) * EDIM + et_ * 16 + l15];                 \
  } while (0)

#define COMP_ITEM(BE, BH, BN, CJ)                                             \
  do {                                                                        \
    float Sr_[8];                                                             \
    _Pragma("unroll")                                                         \
    for (int et_ = 0; et_ < 8; ++et_) Sr_[et_] = 0.f;                         \
    _Pragma("unroll")                                                         \
    for (int t_ = 0; t_ < 2; ++t_) {                                          \
      short8 a_;                                                              \
      if (g < 2) {                                                            \
        u32x4 pk_ = { cvtpk(BE[t_*2].x,   BE[t_*2].y),                        \
                      cvtpk(BE[t_*2].z,   BE[t_*2].w),                        \
                      cvtpk(BE[t_*2+1].x, BE[t_*2+1].y),                      \
                      cvtpk(BE[t_*2+1].z, BE[t_*2+1].w) };                    \
        a_ = __builtin_bit_cast(short8, pk_);                                 \
      } else {                                                                \
        short8 z_ = {0,0,0,0,0,0,0,0};                                        \
        if (g == 2) {                                                         \
          z_[0] = (short)f2bf(BE[t_*2].x);                                    \
          if ((CJ) * 32 + t_ * 16 + l15 >= NN) z_[1] = (short)0x4980;         \
        }                                                                     \
        a_ = z_;                                                              \
      }                                                                       \
      _Pragma("unroll")                                                       \
      for (int et_ = 0; et_ < 8; ++et_) {                                     \
        f32x4 c_ = {BH[et_], BH[et_], BH[et_], BH[et_]};                      \
        c_ = __builtin_amdgcn_mfma_f32_16x16x32_bf16(a_, bfrag[et_], c_, 0, 0, 0); \
        Sr_[et_] += sigr(c_[0]) + sigr(c_[1]) + sigr(c_[2]) + sigr(c_[3]);    \
      }                                                                       \
    }                                                                         \
    _Pragma("unroll")                                                         \
    for (int et_ = 0; et_ < 8; ++et_) {                                       \
      float p_ = Sr_[et_];                                                    \
      p_ += __shfl_xor(p_, 16);                                               \
      p_ += __shfl_xor(p_, 32);                                               \
      Sr_[et_] = p_;                                                          \
    }                                                                         \
    {                                                                         \
      float v0_ = (g == 0) ? Sr_[0] : (g == 1) ? Sr_[1] : (g == 2) ? Sr_[2] : Sr_[3]; \
      float v1_ = (g == 0) ? Sr_[4] : (g == 1) ? Sr_[5] : (g == 2) ? Sr_[6] : Sr_[7]; \
      float* dst_ = part + ((size_t)(CJ) * BN_TOTAL + (BN)) * EDIM;           \
      dst_[lane]      = v0_;                                                  \
      dst_[64 + lane] = v1_;                                                  \
    }                                                                         \
  } while (0)

__global__ __launch_bounds__(64) void msg_kernel(
    const float* __restrict__ ef, const float* __restrict__ Wadj,
    const unsigned short* __restrict__ wcvt,   // W_edge*L + W_weight*L
    const float* __restrict__ hi_arr,          // LAMBDA*hi
    float* __restrict__ part)                  // [7][1600][128]
{
    const int lane = threadIdx.x;
    const int g    = lane >> 4;
    const int l15  = lane & 15;

    // persistent B fragments: k<16 = L*W_edge[e][k]; k16 = L*W_weight[e];
    // k17 = 2^20 (poison channel); rest 0
    short8 bfrag[8];
#pragma unroll
    for (int et = 0; et < 8; ++et) {
        short8 b = {0, 0, 0, 0, 0, 0, 0, 0};
        if (g < 2) b = *(const short8*)(wcvt + (et * 16 + l15) * FDIM + g * 8);
        else if (g == 2) {
            b[0] = (short)wcvt[2048 + et * 16 + l15];
            b[1] = (short)0x4980;                      // bf16 2^20
        }
        bfrag[et] = b;
    }

    const int idx = blockIdx.x * 4;
    int bn_[4], cj_[4];
#pragma unroll
    for (int k = 0; k < 4; ++k) {
        int id = idx + k;
        int b  = (id * 18725) >> 17;                   // id/7 for id < 43690
        bn_[k] = b; cj_[k] = id - b * 7;
    }

    f32x4 beA[4], beB[4];
    float bhA[8], bhB[8];

    LOAD_ITEM(beA, bhA, bn_[0], cj_[0]);
    LOAD_ITEM(beB, bhB, bn_[1], cj_[1]);
    COMP_ITEM(beA, bhA, bn_[0], cj_[0]);
    LOAD_ITEM(beA, bhA, bn_[2], cj_[2]);
    COMP_ITEM(beB, bhB, bn_[1], cj_[1]);
    LOAD_ITEM(beB, bhB, bn_[3], cj_[3]);
    COMP_ITEM(beA, bhA, bn_[2], cj_[2]);
    COMP_ITEM(beB, bhB, bn_[3], cj_[3]);
}

// ---------------------------------------------------------------------------
// outproj: 1600 single-wave blocks, one wave per bn row.
// agg[e] = 1 - 0.01 * sum_j part[j][bn][e]; A-frag gathered via shfl
// (no LDS, no barrier); out = agg @ W_out^T + b_out, coalesced stores.
// ---------------------------------------------------------------------------
__global__ __launch_bounds__(64) void outproj_kernel(
    const float* __restrict__ part, const unsigned short* __restrict__ wout,
    const float* __restrict__ b_out, float* __restrict__ out)
{
    const int lane = threadIdx.x;
    const int g    = lane >> 4;
    const int l15  = lane & 15;
    const int bn   = blockIdx.x;

    float s0 = 0.f, s1 = 0.f;
#pragma unroll
    for (int j = 0; j < NCHUNK; ++j) {
        const float* p = part + ((size_t)j * BN_TOTAL + bn) * EDIM;
        s0 += p[lane];
        s1 += p[64 + lane];
    }
    const float a0 = __builtin_fmaf(-0.01f, s0, 1.0f);   // agg[lane]
    const float a1 = __builtin_fmaf(-0.01f, s1, 1.0f);   // agg[64+lane]

    // A fragments: af[ks] = bf16(agg[ks*32 + g*8 .. +7]), gathered via shfl
    short8 af[4];
#pragma unroll
    for (int ks = 0; ks < 4; ++ks) {
        const float src = (ks < 2) ? a0 : a1;
        const int base = (ks & 1) * 32 + g * 8;
        float t0 = __shfl(src, base + 0, 64);
        float t1 = __shfl(src, base + 1, 64);
        float t2 = __shfl(src, base + 2, 64);
        float t3 = __shfl(src, base + 3, 64);
        float t4 = __shfl(src, base + 4, 64);
        float t5 = __shfl(src, base + 5, 64);
        float t6 = __shfl(src, base + 6, 64);
        float t7 = __shfl(src, base + 7, 64);
        u32x4 pk = { cvtpk(t0, t1), cvtpk(t2, t3), cvtpk(t4, t5), cvtpk(t6, t7) };
        af[ks] = __builtin_bit_cast(short8, pk);
    }

    // out[f] = sum_k agg[k] * W_out[f][k]  (broadcast-row MFMAs, bf16 W_out)
    float o[8];
#pragma unroll
    for (int ft = 0; ft < 8; ++ft) {
        f32x4 acc = {0.f, 0.f, 0.f, 0.f};
#pragma unroll
        for (int ks = 0; ks < 4; ++ks) {
            short8 b = *(const short8*)(wout + (ft * 16 + l15) * EDIM + ks * 32 + g * 8);
            acc = __builtin_amdgcn_mfma_f32_16x16x32_bf16(af[ks], b, acc, 0, 0, 0);
        }
        o[ft] = acc[0];                      // all D rows equal
    }

    const float v0 = (g == 0) ? o[0] : (g == 1) ? o[1] : (g == 2) ? o[2] : o[3];
    const float v1 = (g == 0) ? o[4] : (g == 1) ? o[5] : (g == 2) ? o[6] : o[7];
    out[(size_t)bn * EDIM + lane]      = v0 + b_out[lane];
    out[(size_t)bn * EDIM + 64 + lane] = v1 + b_out[64 + lane];
}

extern "C" void kernel_launch(void* const* d_in, const int* in_sizes, int n_in,
                              void* d_out, int out_size, void* d_ws, size_t ws_size,
                              hipStream_t stream) {
    const float* h        = (const float*)d_in[0];
    const float* ef       = (const float*)d_in[1];
    const float* W        = (const float*)d_in[2];
    const float* W_node   = (const float*)d_in[3];
    const float* W_edge   = (const float*)d_in[4];
    const float* W_weight = (const float*)d_in[5];
    const float* W_out    = (const float*)d_in[6];
    const float* b_out    = (const float*)d_in[7];
    float* out = (float*)d_out;

    unsigned short* wsb = (unsigned short*)d_ws;
    float*          wsf = (float*)d_ws;
    unsigned short* wcvt   = wsb;              // W_edge + W_weight (bf16, *LAMBDA)
    unsigned short* wout   = wsb + WS_WOUT_S;  // W_out bf16
    float*          hi_arr = wsf + WSF_HI;     // LAMBDA*hi
    float*          part   = wsf + WSF_PART;   // [7][1600][128]

    setup_kernel<<<208, 128, 0, stream>>>(h, W_node, W_edge, W_weight, W_out,
                                          wcvt, wout, hi_arr);
    msg_kernel<<<MSG_BLOCKS, 64, 0, stream>>>(ef, W, wcvt, hi_arr, part);
    outproj_kernel<<<BN_TOTAL, 64, 0, stream>>>(part, wout, b_out, out);
}